// Round 10
// baseline (572.384 us; speedup 1.0000x reference)
//
#include <hip/hip_runtime.h>
#include <math.h>
#include <stdint.h>

#define BATCH 64
#define T 256
#define NF 64
#define H 128
#define H4 512                    // 4*H
#define HP1 129
#define WF_STRIDE (HP1 * H4)      // 66048 floats per feature
#define FEATS (NF * H + H)        // 8320
#define NTH4 1024                 // 16 waves: 2 groups x 8 waves

// pack2: uint4 idx = ((f*8 + w)*8 + i)*64 + l   (4 MB) [R8 layout, verified]
#define PACK2_U4 (64 * 8 * 2 * 4 * 64)
#define PACK2_BYTES ((size_t)PACK2_U4 * 16u)
#define HDR2_BYTES  (64u * 512u * 16u)                   // 512 KB [R8, verified]
#define WS_NEED ((size_t)HDR2_BYTES + PACK2_BYTES)       // 4.5 MB

typedef float vf2 __attribute__((ext_vector_type(2)));

__device__ __forceinline__ float sigmoidf_(float x) {
    return 1.0f / (1.0f + __expf(-x));
}

__device__ __forceinline__ float tanhf_(float x) {
    float ax = fabsf(x);
    float e = __expf(2.0f * ax);              // inf for large ax -> r = 1
    float r = 1.0f - 2.0f / (e + 1.0f);
    return copysignf(r, x);
}

template<bool HI>
__device__ __forceinline__ vf2 dec2f(unsigned u) {
    return __builtin_amdgcn_cvt_pk_f32_fp8(u, HI);
}

__device__ __forceinline__ void dma16(const void* g, uint32_t lds_byte) {
    __builtin_amdgcn_global_load_lds(
        (const __attribute__((address_space(1))) void*)g,
        (__attribute__((address_space(3))) void*)(uintptr_t)lds_byte,
        16, 0, 0);
}

#define WAITV0() do { asm volatile("s_waitcnt vmcnt(0)" ::: "memory"); \
                      __builtin_amdgcn_sched_barrier(0); } while (0)
#define LGKM0()  do { asm volatile("s_waitcnt lgkmcnt(0)" ::: "memory"); \
                      __builtin_amdgcn_sched_barrier(0); } while (0)
#define BARRIER() do { asm volatile("s_waitcnt lgkmcnt(0)" ::: "memory"); \
                       __builtin_amdgcn_s_barrier(); \
                       asm volatile("" ::: "memory"); } while (0)

// ===== repack2 (verbatim R8, absmax-0-verified): fp8 x4096, slice layout =====
__global__ __launch_bounds__(256)
void repack2_kernel(const float* __restrict__ W_lin, uint4* __restrict__ pack2) {
    const int lin = blockIdx.x * 256 + threadIdx.x;   // 0..262143
    const int l   = lin & 63;
    const int i   = (lin >> 6) & 3;
    const int Xv  = (lin >> 8) & 1;
    const int wv  = (lin >> 9) & 7;
    const int f   = lin >> 12;
    const int h   = wv * 16 + (l & 15);
    const int ks  = l >> 4;
    const int g   = Xv * 2 + (i >> 1);
    const int ksub = i & 1;
    const int col = g * 128 + h;
    const int k0  = ks * 32 + ksub * 16;
    const float* src = W_lin + (size_t)f * WF_STRIDE + (size_t)(1 + k0) * H4 + col;
    unsigned u[4];
    #pragma unroll
    for (int dw = 0; dw < 4; ++dw) {
        const float v0 = src[(4 * dw + 0) * H4] * 4096.0f;
        const float v1 = src[(4 * dw + 1) * H4] * 4096.0f;
        const float v2 = src[(4 * dw + 2) * H4] * 4096.0f;
        const float v3 = src[(4 * dw + 3) * H4] * 4096.0f;
        unsigned r = 0;
        r = __builtin_amdgcn_cvt_pk_fp8_f32(v0, v1, r, false);
        r = __builtin_amdgcn_cvt_pk_fp8_f32(v2, v3, r, true);
        u[dw] = r;
    }
    uint4 o; o.x = u[0]; o.y = u[1]; o.z = u[2]; o.w = u[3];
    pack2[lin] = o;
}

// hdr2 (verbatim R8): uint4 of 8 fp16 {wx[0..3], b[0..3]} per (f, w*64+l)
__global__ __launch_bounds__(256)
void hdr2_kernel(const float* __restrict__ W_lin, const float* __restrict__ b_lin,
                 uint4* __restrict__ hdr2) {
    const int lin = blockIdx.x * 256 + threadIdx.x;   // 0..32767
    const int t2 = lin & 511, f = lin >> 9;
    const int wv = t2 >> 6, l = t2 & 63;
    const int h  = wv * 16 + (l & 15);
    union { uint4 u; _Float16 hf[8]; } o;
    #pragma unroll
    for (int g = 0; g < 4; ++g) {
        o.hf[g]     = (_Float16)W_lin[(size_t)f * WF_STRIDE + g * 128 + h];
        o.hf[4 + g] = (_Float16)b_lin[f * H4 + g * 128 + h];
    }
    hdr2[lin] = o.u;
}

// ===== main scan: 2 steps/iteration + LDS-DMA weight prefetch ===============
// R9's pairing (scalar logic verified) + R8's global_load_lds prefetch
// (un-sinkable, waits ~0). Group g (8 waves) computes step 2i+g's matvec from
// its own 64KB LDS region, staged one ITERATION ahead; per-wave disjoint 8KB
// slices -> no staging barriers, per-wave WAITV(0) at iteration top. One
// serial-chain traversal (2 barriers) now covers TWO timesteps.
__global__ __launch_bounds__(NTH4, 4)
void lstm_scan_fp8_pair2(const float* __restrict__ X,
                         const int* __restrict__ lengths,
                         const float* __restrict__ W_dec,
                         const float* __restrict__ b_dec,
                         const float* __restrict__ W_out,
                         const float* __restrict__ b_out,
                         const uint4* __restrict__ pack2,
                         const uint4* __restrict__ hdr2,
                         float* __restrict__ out)
{
    __shared__ __align__(16) char s_wb[131072];   // 2 regions x 64KB
    __shared__ _Float16 s_ht[NF * H];             // 16 KB h table (fp16)
    __shared__ __align__(16) float s_gates[2][H][4];  // 4 KB
    __shared__ float s_X[4 * T];
    __shared__ float s_inpA[H];
    __shared__ float s_inpB[H];
    __shared__ float s_wdec[NF];
    __shared__ float s_bdec[NF];
    __shared__ float s_cfin[H];
    __shared__ float s_red[32];

    const int tid = threadIdx.x;
    const int b   = blockIdx.x;
    const int grp = tid >> 9;             // 0: step j, 1: step j+1
    const int w8  = (tid >> 6) & 7;
    const int l   = tid & 63;
    const int h   = w8 * 16 + (l & 15);
    const int ks  = l >> 4;

    const float* Xb = X + b * 4 * T;
    const int len = lengths[b];

    for (int i = tid; i < NF * H; i += NTH4) s_ht[i] = (_Float16)0.0f;
    for (int i = tid; i < 4 * T; i += NTH4) s_X[i] = Xb[i];
    if (tid < NF) { s_wdec[tid] = W_dec[tid]; s_bdec[tid] = b_dec[tid]; }
    if (tid < H) { s_inpA[tid] = 0.0f; s_inpB[tid] = 0.0f; }
    __syncthreads();

    const uint32_t wb0 = (uint32_t)(uintptr_t)s_wb;
    const uint32_t slice = __builtin_amdgcn_readfirstlane(
        wb0 + (uint32_t)grp * 65536u + (uint32_t)w8 * 8192u);

    float c_t = 0.0f, accv = 0.0f, cntv = 0.0f;

    #define ISSUE8(MF) do {                                                     \
        const uint4* gp_ = pack2 + ((size_t)(MF) * 8 + w8) * 512 + l;           \
        _Pragma("unroll")                                                       \
        for (int ii = 0; ii < 8; ++ii)                                          \
            dma16(gp_ + ii * 64, slice + (uint32_t)(ii * 1024));                \
    } while (0)

    #define DOTQ(Wq, G, KS) do {                                                \
        const int pb = (KS) * 8;                                                \
        vf2 d;                                                                  \
        d = dec2f<false>((Wq).x); acc[G] += d * iv[pb + 0];                     \
        d = dec2f<true >((Wq).x); acc[G] += d * iv[pb + 1];                     \
        d = dec2f<false>((Wq).y); acc[G] += d * iv[pb + 2];                     \
        d = dec2f<true >((Wq).y); acc[G] += d * iv[pb + 3];                     \
        d = dec2f<false>((Wq).z); acc[G] += d * iv[pb + 4];                     \
        d = dec2f<true >((Wq).z); acc[G] += d * iv[pb + 5];                     \
        d = dec2f<false>((Wq).w); acc[G] += d * iv[pb + 6];                     \
        d = dec2f<true >((Wq).w); acc[G] += d * iv[pb + 7];                     \
    } while (0)

    // read own 8KB slice (8 uint4) via asm ds_read, dot vs INP, combine w/ HU
    #define MATVEC_LDS(INP, XV, HU, GATE) do {                                  \
        uint4 q0, q1, q2, q3, q4, q5, q6, q7;                                   \
        const uint32_t ra_ = wb0 + (uint32_t)grp * 65536u                       \
                           + (uint32_t)w8 * 8192u + (uint32_t)l * 16u;          \
        asm volatile("ds_read_b128 %0, %4 offset:0\n\t"                         \
                     "ds_read_b128 %1, %4 offset:1024\n\t"                      \
                     "ds_read_b128 %2, %4 offset:2048\n\t"                      \
                     "ds_read_b128 %3, %4 offset:3072"                          \
                     : "=&v"(q0), "=&v"(q1), "=&v"(q2), "=&v"(q3)               \
                     : "v"(ra_) : "memory");                                    \
        asm volatile("ds_read_b128 %0, %4 offset:4096\n\t"                      \
                     "ds_read_b128 %1, %4 offset:5120\n\t"                      \
                     "ds_read_b128 %2, %4 offset:6144\n\t"                      \
                     "ds_read_b128 %3, %4 offset:7168"                          \
                     : "=&v"(q4), "=&v"(q5), "=&v"(q6), "=&v"(q7)               \
                     : "v"(ra_) : "memory");                                    \
        vf2 iv[16];                                                             \
        {                                                                       \
            const float4* ip_ = (const float4*)((INP) + ks * 32);               \
            _Pragma("unroll")                                                   \
            for (int qd = 0; qd < 8; ++qd) {                                    \
                const float4 t_ = ip_[qd];                                      \
                iv[2 * qd][0] = t_.x;     iv[2 * qd][1] = t_.y;                 \
                iv[2 * qd + 1][0] = t_.z; iv[2 * qd + 1][1] = t_.w;             \
            }                                                                   \
        }                                                                       \
        LGKM0();  /* q regs + iv retired: slice now safe to overwrite */        \
        vf2 acc[4];                                                             \
        _Pragma("unroll")                                                       \
        for (int g = 0; g < 4; ++g) { acc[g][0] = 0.0f; acc[g][1] = 0.0f; }     \
        DOTQ(q0, 0, 0); DOTQ(q1, 0, 1); DOTQ(q2, 1, 0); DOTQ(q3, 1, 1);         \
        DOTQ(q4, 2, 0); DOTQ(q5, 2, 1); DOTQ(q6, 3, 0); DOTQ(q7, 3, 1);         \
        _Pragma("unroll")                                                       \
        for (int g = 0; g < 4; ++g) {                                           \
            float s_ = acc[g][0] + acc[g][1];                                   \
            s_ += __shfl_xor(s_, 16, 64);                                       \
            s_ += __shfl_xor(s_, 32, 64);                                       \
            GATE[g] = fmaf(s_, 1.0f / 4096.0f,                                  \
                           fmaf((XV), (float)(HU).hf[g], (float)(HU).hf[4 + g])); \
        }                                                                       \
    } while (0)

    // prologue: stage iteration 0 (grp0: step 0, grp1: step 1)
    {
        const int m0 = (int)s_X[T];
        const int m1 = (int)s_X[T + ((1 < T) ? 1 : (T - 1))];
        ISSUE8(grp ? m1 : m0);
    }

    for (int j = 0; j < len; j += 2) {
        const int  vj1 = (j + 1 < len);
        const int  mj  = (int)s_X[T + j];
        const int  j1c = (j + 1 < T) ? (j + 1) : (T - 1);
        const int  mj1 = (int)s_X[T + j1c];
        const float xj  = s_X[2 * T + j];
        const float xj1 = s_X[2 * T + j1c];
        const bool coll = vj1 && (mj1 == mj);      // block-uniform
        const int  j2 = (j + 2 < T) ? (j + 2) : (T - 1);
        const int  j3 = (j + 3 < T) ? (j + 3) : (T - 1);
        const int  m2 = (int)s_X[T + j2];
        const int  m3 = (int)s_X[T + j3];

        const int   myM   = grp ? mj1 : mj;
        const float myx   = grp ? xj1 : xj;
        const float* myin = grp ? s_inpB : s_inpA;

        // hdr for my step (L2-resident, consumed after matvec VALU)
        union { uint4 u; _Float16 hf[8]; } hu;
        hu.u = hdr2[(size_t)myM * 512 + (w8 * 64 + l)];

        WAITV0();   // my slice's DMA (issued last iteration) complete

        float gate[4];
        MATVEC_LDS(myin, myx, hu, gate);

        // stage next iteration (slice reads retired inside MATVEC_LDS).
        // grp1 delays to after collision recompute (reads its slice again).
        if (grp == 0) ISSUE8(m2);
        else if (!coll) ISSUE8(m3);

        if (ks == 0) {
            float4 g4; g4.x = gate[0]; g4.y = gate[1]; g4.z = gate[2]; g4.w = gate[3];
            *(float4*)&s_gates[grp][h][0] = g4;
        }
        BARRIER();   // gates visible (vmcnt alive)

        // ---- scalar phase (all lanes, redundant) ----
        const float4 gA = *(const float4*)&s_gates[0][h][0];
        float4 gB = *(const float4*)&s_gates[1][h][0];

        const float c_candA = sigmoidf_(gA.y) * c_t + sigmoidf_(gA.x) * tanhf_(gA.w);
        const float h_rowA  = sigmoidf_(gA.z) * tanhf_(c_candA);
        accv += c_candA;
        cntv += 1.0f;
        {
            const float tj  = s_X[j];
            const float tn1 = (j < T - 1) ? s_X[j + 1] : (tj + 1.0f);
            const bool bdry = (j == len - 1) || (tn1 != tj);
            if (bdry) { c_t = accv / fmaxf(cntv, 1.0f); accv = 0.0f; cntv = 0.0f; }
        }

        if (coll) {
            const float d1  = s_X[3 * T + j1c];
            const float dm1 = fmaf(s_wdec[mj1], d1, s_bdec[mj1]);
            const float de1 = __expf(-fmaxf(0.0f, dm1));
            if (grp == 1 && ks == 0) s_inpB[h] = de1 * h_rowA;
            BARRIER();
            if (grp == 1) {
                float gr[4];
                MATVEC_LDS(s_inpB, xj1, hu, gr);   // slice intact (DMA delayed)
                ISSUE8(m3);                        // now safe to overwrite
                if (ks == 0) {
                    float4 g4; g4.x = gr[0]; g4.y = gr[1]; g4.z = gr[2]; g4.w = gr[3];
                    *(float4*)&s_gates[1][h][0] = g4;
                }
            }
            BARRIER();
            gB = *(const float4*)&s_gates[1][h][0];
        }

        float h_rowB = 0.0f;
        if (vj1) {
            const float c_candB = sigmoidf_(gB.y) * c_t + sigmoidf_(gB.x) * tanhf_(gB.w);
            h_rowB = sigmoidf_(gB.z) * tanhf_(c_candB);
            accv += c_candB;
            cntv += 1.0f;
            const float tj1 = s_X[j1c];
            const float tn2 = (j + 1 < T - 1) ? s_X[j + 2] : (tj1 + 1.0f);
            const bool bdry = (j + 1 == len - 1) || (tn2 != tj1);
            if (bdry) { c_t = accv / fmaxf(cntv, 1.0f); accv = 0.0f; cntv = 0.0f; }
        }

        if (ks == 0) {
            if (grp == 0 && !coll) s_ht[mj * H + h] = (_Float16)h_rowA;
            if (grp == 1 && vj1)   s_ht[mj1 * H + h] = (_Float16)h_rowB;
        }

        // stage next pair's inputs (register-forward just-written rows)
        if (ks == 0 && grp == 0) {
            const float d2  = s_X[3 * T + j2];
            const float dm2 = fmaf(s_wdec[m2], d2, s_bdec[m2]);
            const float de2 = __expf(-fmaxf(0.0f, dm2));
            const float hv2 = (vj1 && m2 == mj1) ? h_rowB
                            : ((m2 == mj) ? h_rowA : (float)s_ht[m2 * H + h]);
            s_inpA[h] = de2 * hv2;
        }
        if (ks == 0 && grp == 1) {
            const float d3  = s_X[3 * T + j3];
            const float dm3 = fmaf(s_wdec[m3], d3, s_bdec[m3]);
            const float de3 = __expf(-fmaxf(0.0f, dm3));
            const float hv3 = (vj1 && m3 == mj1) ? h_rowB
                            : ((m3 == mj) ? h_rowA : (float)s_ht[m3 * H + h]);
            s_inpB[h] = de3 * hv3;
        }
        BARRIER();
    }
    #undef MATVEC_LDS
    #undef DOTQ
    #undef ISSUE8

    asm volatile("s_waitcnt vmcnt(0) lgkmcnt(0)" ::: "memory");
    __syncthreads();

    // ---- epilogue ----
    if (grp == 0 && ks == 0) s_cfin[h] = c_t;
    __syncthreads();

    float z0 = 0.0f, z1 = 0.0f;
    for (int i = tid; i < FEATS; i += NTH4) {
        const float f = (i < H) ? s_cfin[i] : (float)s_ht[i - H];
        const float2 wo = *(const float2*)(W_out + 2 * i);
        z0 = fmaf(f, wo.x, z0);
        z1 = fmaf(f, wo.y, z1);
    }
    #pragma unroll
    for (int off = 32; off > 0; off >>= 1) {
        z0 += __shfl_down(z0, off, 64);
        z1 += __shfl_down(z1, off, 64);
    }
    const int wave = tid >> 6, lane2 = tid & 63;
    if (lane2 == 0) { s_red[2 * wave] = z0; s_red[2 * wave + 1] = z1; }
    __syncthreads();
    if (tid == 0) {
        float a0 = b_out[0], a1 = b_out[1];
        #pragma unroll
        for (int q = 0; q < 16; ++q) { a0 += s_red[2 * q]; a1 += s_red[2 * q + 1]; }
        const float mx = fmaxf(a0, a1);
        const float e0 = __expf(a0 - mx), e1 = __expf(a1 - mx);
        const float inv = 1.0f / (e0 + e1);
        out[2 * b]     = e0 * inv;
        out[2 * b + 1] = e1 * inv;
    }
}

// ---------------- fp32 fallback (no-workspace path) ----------------
#define NTHREADS 512
__global__ __launch_bounds__(NTHREADS)
void lstm_scan_kernel(const float* __restrict__ X,
                      const int* __restrict__ lengths,
                      const float* __restrict__ W_lin,
                      const float* __restrict__ b_lin,
                      const float* __restrict__ W_dec,
                      const float* __restrict__ b_dec,
                      const float* __restrict__ W_out,
                      const float* __restrict__ b_out,
                      float* __restrict__ out)
{
    __shared__ float s_feats[FEATS];
    __shared__ float s_inp[H];
    __shared__ float s_part[4][H4];
    __shared__ float s_X[4 * T];
    __shared__ float s_wdec[NF];
    __shared__ float s_bdec[NF];
    __shared__ float s_red[16];

    float* s_ct = s_feats;
    float* s_ht = s_feats + H;

    const int tid = threadIdx.x;
    const int b   = blockIdx.x;
    const int g4  = tid & 127;
    const int kq  = tid >> 7;

    const float* Xb = X + b * 4 * T;
    const int len = lengths[b];

    for (int i = tid; i < NF * H; i += NTHREADS) s_ht[i] = 0.0f;
    for (int i = tid; i < 4 * T; i += NTHREADS) s_X[i] = Xb[i];
    if (tid < NF) { s_wdec[tid] = W_dec[tid]; s_bdec[tid] = b_dec[tid]; }
    __syncthreads();

    float c_t = 0.0f, acc = 0.0f, cnt = 0.0f;

    for (int j = 0; j < len; ++j) {
        const int   mj = (int)s_X[T + j];
        const float xj = s_X[2 * T + j];
        const float* Wf = W_lin + mj * WF_STRIDE;

        float bl0, bl1, bl2, bl3;
        if (tid < H) {
            const float dj    = s_X[3 * T + j];
            const float dm    = fmaf(s_wdec[mj], dj, s_bdec[mj]);
            const float decay = __expf(-fmaxf(0.0f, dm));
            s_inp[tid] = decay * s_ht[mj * H + tid];
            const int m4 = mj * H4;
            bl0 = b_lin[m4 + tid];
            bl1 = b_lin[m4 + H + tid];
            bl2 = b_lin[m4 + 2 * H + tid];
            bl3 = b_lin[m4 + 3 * H + tid];
        }
        __syncthreads();

        float4 a4 = make_float4(0.0f, 0.0f, 0.0f, 0.0f);
        {
            const float*  wr  = Wf + (1 + kq * 32) * H4 + 4 * g4;
            const float4* ivp = (const float4*)(s_inp + kq * 32);
            #pragma unroll
            for (int cc = 0; cc < 8; ++cc) {
                const float4 v = ivp[cc];
                const float* wrc = wr + (4 * cc) * H4;
                const float4 w0 = *(const float4*)(wrc);
                const float4 w1 = *(const float4*)(wrc + H4);
                const float4 w2 = *(const float4*)(wrc + 2 * H4);
                const float4 w3 = *(const float4*)(wrc + 3 * H4);
                a4.x = fmaf(v.x, w0.x, a4.x); a4.y = fmaf(v.x, w0.y, a4.y);
                a4.z = fmaf(v.x, w0.z, a4.z); a4.w = fmaf(v.x, w0.w, a4.w);
                a4.x = fmaf(v.y, w1.x, a4.x); a4.y = fmaf(v.y, w1.y, a4.y);
                a4.z = fmaf(v.y, w1.z, a4.z); a4.w = fmaf(v.y, w1.w, a4.w);
                a4.x = fmaf(v.z, w2.x, a4.x); a4.y = fmaf(v.z, w2.y, a4.y);
                a4.z = fmaf(v.z, w2.z, a4.z); a4.w = fmaf(v.z, w2.w, a4.w);
                a4.x = fmaf(v.w, w3.x, a4.x); a4.y = fmaf(v.w, w3.y, a4.y);
                a4.z = fmaf(v.w, w3.z, a4.z); a4.w = fmaf(v.w, w3.w, a4.w);
            }
        }
        if (kq == 0) {
            const float4 wv = *(const float4*)(Wf + 4 * g4);
            a4.x = fmaf(xj, wv.x, a4.x); a4.y = fmaf(xj, wv.y, a4.y);
            a4.z = fmaf(xj, wv.z, a4.z); a4.w = fmaf(xj, wv.w, a4.w);
        }
        *(float4*)(&s_part[kq][4 * g4]) = a4;
        __syncthreads();

        if (tid < H) {
            const int h = tid;
            const float gi = s_part[0][h]         + s_part[1][h]         + s_part[2][h]         + s_part[3][h]         + bl0;
            const float gf = s_part[0][H + h]     + s_part[1][H + h]     + s_part[2][H + h]     + s_part[3][H + h]     + bl1;
            const float go = s_part[0][2*H + h]   + s_part[1][2*H + h]   + s_part[2][2*H + h]   + s_part[3][2*H + h]   + bl2;
            const float gc = s_part[0][3*H + h]   + s_part[1][3*H + h]   + s_part[2][3*H + h]   + s_part[3][3*H + h]   + bl3;

            const float c_cand = sigmoidf_(gf) * c_t + sigmoidf_(gi) * tanhf_(gc);
            const float h_row  = sigmoidf_(go) * tanhf_(c_cand);
            s_ht[mj * H + h] = h_row;
            acc += c_cand;
            cnt += 1.0f;

            const float tj = s_X[j];
            const float tn = (j < T - 1) ? s_X[j + 1] : (tj + 1.0f);
            const bool boundary = (j == len - 1) || (tn != tj);
            if (boundary) { c_t = acc / fmaxf(cnt, 1.0f); acc = 0.0f; cnt = 0.0f; }
        }
        __syncthreads();
    }

    if (tid < H) s_ct[tid] = c_t;
    __syncthreads();

    float z0 = 0.0f, z1 = 0.0f;
    for (int i = tid; i < FEATS; i += NTHREADS) {
        const float f = s_feats[i];
        const float2 wv = *(const float2*)(W_out + 2 * i);
        z0 = fmaf(f, wv.x, z0);
        z1 = fmaf(f, wv.y, z1);
    }
    #pragma unroll
    for (int off = 32; off > 0; off >>= 1) {
        z0 += __shfl_down(z0, off, 64);
        z1 += __shfl_down(z1, off, 64);
    }
    const int wave = tid >> 6, lane = tid & 63;
    if (lane == 0) { s_red[2 * wave] = z0; s_red[2 * wave + 1] = z1; }
    __syncthreads();
    if (tid == 0) {
        float a0 = b_out[0], a1 = b_out[1];
        #pragma unroll
        for (int q = 0; q < 8; ++q) { a0 += s_red[2 * q]; a1 += s_red[2 * q + 1]; }
        const float mx = fmaxf(a0, a1);
        const float e0 = __expf(a0 - mx), e1 = __expf(a1 - mx);
        const float inv = 1.0f / (e0 + e1);
        out[2 * b]     = e0 * inv;
        out[2 * b + 1] = e1 * inv;
    }
}

extern "C" void kernel_launch(void* const* d_in, const int* in_sizes, int n_in,
                              void* d_out, int out_size, void* d_ws, size_t ws_size,
                              hipStream_t stream) {
    const float* X      = (const float*)d_in[0];
    const int*   lens   = (const int*)d_in[1];
    const float* W_lin  = (const float*)d_in[2];
    const float* b_lin  = (const float*)d_in[3];
    const float* W_dec  = (const float*)d_in[4];
    const float* b_dec  = (const float*)d_in[5];
    const float* W_out  = (const float*)d_in[6];
    const float* b_out  = (const float*)d_in[7];
    float* out = (float*)d_out;

    if (ws_size >= WS_NEED) {
        uint4* hdr2 = (uint4*)d_ws;
        uint4* pack2 = (uint4*)((char*)d_ws + HDR2_BYTES);
        hipLaunchKernelGGL(hdr2_kernel, dim3(128), dim3(256), 0, stream,
                           W_lin, b_lin, hdr2);
        hipLaunchKernelGGL(repack2_kernel, dim3(PACK2_U4 / 256), dim3(256), 0, stream,
                           W_lin, pack2);
        hipLaunchKernelGGL(lstm_scan_fp8_pair2, dim3(BATCH), dim3(NTH4), 0, stream,
                           X, lens, W_dec, b_dec, W_out, b_out, pack2, hdr2, out);
    } else {
        hipLaunchKernelGGL(lstm_scan_kernel, dim3(BATCH), dim3(NTHREADS), 0, stream,
                           X, lens, W_lin, b_lin, W_dec, b_dec, W_out, b_out, out);
    }
}

// Round 11
// 448.840 us; speedup vs baseline: 1.2753x; 1.2753x over previous
//
#include <hip/hip_runtime.h>
#include <math.h>
#include <stdint.h>

#define BATCH 64
#define T 256
#define NF 64
#define H 128
#define H4 512                    // 4*H
#define HP1 129
#define WF_STRIDE (HP1 * H4)      // 66048 floats per feature
#define FEATS (NF * H + H)        // 8320
#define NTH 1024                  // 16 waves

// fp8 pack (R6 layout, absmax-0-verified): ((f*2+h)*2+q)*1024 + tid
#define PACK8_U4 (64 * 2 * 2 * 1024)                 // 262144 uint4
#define PACK8_BYTES ((size_t)PACK8_U4 * 16u)         // 4 MB

typedef float vf2 __attribute__((ext_vector_type(2)));

__device__ __forceinline__ float sigmoidf_(float x) {
    return 1.0f / (1.0f + __expf(-x));
}

__device__ __forceinline__ float tanhf_(float x) {
    float ax = fabsf(x);
    float e = __expf(2.0f * ax);              // inf for large ax -> r = 1
    float r = 1.0f - 2.0f / (e + 1.0f);
    return copysignf(r, x);
}

// decode 2 fp8 bytes of a dword -> float2 (HI must be literal)
template<bool HI>
__device__ __forceinline__ vf2 dec2f(unsigned u) {
    return __builtin_amdgcn_cvt_pk_f32_fp8(u, HI);
}

// ===== repack8 (verbatim R6, absmax-0-verified): fp8 x4096 ==================
// pack[((f*2+h)*2+q)*1024 + tid], tid: kh=tid>>9, c=tid&511.
// byte r of dword w of the uint4 <-> k = h*64 + kh*32 + q*16 + 4w + r,
// value = fp8_e4m3( W_lin[f][1+k][c] * 4096 )
__global__ __launch_bounds__(256)
void repack8_kernel(const float* __restrict__ W_lin, uint4* __restrict__ pack) {
    const int lin = blockIdx.x * 256 + threadIdx.x;   // 0..262143
    const int tid = lin & 1023;
    const int q   = (lin >> 10) & 1;
    const int h   = (lin >> 11) & 1;
    const int f   = lin >> 12;
    const int kh  = tid >> 9;
    const int cc  = tid & 511;
    const int k0  = h * 64 + kh * 32 + q * 16;
    const float* src = W_lin + (size_t)f * WF_STRIDE + (size_t)(1 + k0) * H4 + cc;
    unsigned u[4];
    #pragma unroll
    for (int w = 0; w < 4; ++w) {
        const float v0 = src[(4 * w + 0) * H4] * 4096.0f;
        const float v1 = src[(4 * w + 1) * H4] * 4096.0f;
        const float v2 = src[(4 * w + 2) * H4] * 4096.0f;
        const float v3 = src[(4 * w + 3) * H4] * 4096.0f;
        unsigned r = 0;
        r = __builtin_amdgcn_cvt_pk_fp8_f32(v0, v1, r, false);
        r = __builtin_amdgcn_cvt_pk_fp8_f32(v2, v3, r, true);
        u[w] = r;
    }
    uint4 o; o.x = u[0]; o.y = u[1]; o.z = u[2]; o.w = u[3];
    pack[lin] = o;
}

// ===== main scan: R6 skeleton + full weight double-buffer + packed-f32 math ==
// Per thread per step: 4 uint4 of fp8 (64 k's for column c), ALL prefetched one
// step ahead (8 uint4 = 32 VGPR double-buffer -- the scale R6's compiler kept
// in VGPRs). Decode: cvt_pk_f32_fp8 (1 inst -> 2 f32) + vf2 FMA (2 MACs/inst)
// vs f32 inputs read at wave-uniform LDS addresses (broadcast). Removes R6's
// in-step half1 latency (~600cy) and 1/3 of its decode VALU.
__global__ __launch_bounds__(NTH, 2)
void lstm_scan_fp8_v2(const float* __restrict__ X,
                      const int* __restrict__ lengths,
                      const float* __restrict__ W_lin,
                      const float* __restrict__ b_lin,
                      const float* __restrict__ W_dec,
                      const float* __restrict__ b_dec,
                      const float* __restrict__ W_out,
                      const float* __restrict__ b_out,
                      const uint4* __restrict__ pack,
                      float* __restrict__ out)
{
    __shared__ float s_feats[FEATS];          // [0,H)=c_t, [H,..)=h_t row-major
    __shared__ float s_inp[H];                // decayed hidden row (f32)
    __shared__ float s_part[2][H4];           // K-half matvec partials
    __shared__ float s_X[4 * T];
    __shared__ float s_wdec[NF];
    __shared__ float s_bdec[NF];
    __shared__ float s_red[32];

    float* s_ct = s_feats;
    float* s_ht = s_feats + H;

    const int tid = threadIdx.x;
    const int b   = blockIdx.x;
    const int c   = tid & 511;                // gate column
    const int kh  = tid >> 9;                 // K half (0/1), wave-uniform

    const float* Xb = X + b * 4 * T;
    const int len = lengths[b];

    for (int i = tid; i < NF * H; i += NTH) s_ht[i] = 0.0f;
    for (int i = tid; i < 4 * T; i += NTH) s_X[i] = Xb[i];
    if (tid < NF) { s_wdec[tid] = W_dec[tid]; s_bdec[tid] = b_dec[tid]; }
    if (tid < H) s_inp[tid] = 0.0f;
    __syncthreads();

    float c_t = 0.0f, accs = 0.0f, cnts = 0.0f;

    // dot of one weight-uint4 (16 fp8 k's starting at K0) vs f32 input pairs.
    // Input addresses are wave-uniform (kh constant per wave) -> LDS broadcast.
    #define DOTF(W, K0) do {                                                    \
        const vf2* ip = (const vf2*)(s_inp + (K0));                             \
        vf2 d;                                                                  \
        d = dec2f<false>((W).x); acc += d * ip[0];                              \
        d = dec2f<true >((W).x); acc += d * ip[1];                              \
        d = dec2f<false>((W).y); acc += d * ip[2];                              \
        d = dec2f<true >((W).y); acc += d * ip[3];                              \
        d = dec2f<false>((W).z); acc += d * ip[4];                              \
        d = dec2f<true >((W).z); acc += d * ip[5];                              \
        d = dec2f<false>((W).w); acc += d * ip[6];                              \
        d = dec2f<true >((W).w); acc += d * ip[7];                              \
    } while (0)

    uint4 A0, A1, A2, A3, B0, B1, B2, B3;     // full step double-buffer
    float4 blA = make_float4(0.f, 0.f, 0.f, 0.f), blB = make_float4(0.f, 0.f, 0.f, 0.f);
    float  wxA = 0.0f, wxB = 0.0f;

    // prologue: prefetch step 0 (all 4 weight uint4 + bias + x-row)
    {
        const int m0 = (int)s_X[T];
        const uint4* p0 = pack + (size_t)m0 * 4096 + tid;
        A0 = p0[0]; A1 = p0[1024]; A2 = p0[2048]; A3 = p0[3072];
        if (tid < H) {
            const float* bb = b_lin + m0 * H4 + tid;
            blA.x = bb[0]; blA.y = bb[H]; blA.z = bb[2 * H]; blA.w = bb[3 * H];
        }
        if (kh == 0) wxA = W_lin[(size_t)m0 * WF_STRIDE + c];
    }

    #define STEP(C0, C1, C2, C3, N0, N1, N2, N3, CBL, NBL, CWX, NWX)            \
    {                                                                           \
        const int   mj  = (int)s_X[T + j];                                      \
        const float xj  = s_X[2 * T + j];                                       \
        const int   jn  = (j + 1 < T) ? (j + 1) : (T - 1);                      \
        const int   mjn = (int)s_X[T + jn];                                     \
        /* prefetch next step (consumed NEXT iteration; drained at barrier A) */\
        {                                                                       \
            const uint4* pn = pack + (size_t)mjn * 4096 + tid;                  \
            N0 = pn[0]; N1 = pn[1024]; N2 = pn[2048]; N3 = pn[3072];            \
        }                                                                       \
        if (tid < H) {                                                          \
            const float* bb = b_lin + mjn * H4 + tid;                           \
            NBL.x = bb[0]; NBL.y = bb[H]; NBL.z = bb[2 * H]; NBL.w = bb[3 * H]; \
        }                                                                       \
        if (kh == 0) NWX = W_lin[(size_t)mjn * WF_STRIDE + c];                  \
        /* matvec over registers prefetched LAST step; k = h*64+kh*32+q*16 */   \
        vf2 acc; acc[0] = 0.0f; acc[1] = 0.0f;                                  \
        DOTF(C0, kh * 32);                                                      \
        DOTF(C1, kh * 32 + 16);                                                 \
        DOTF(C2, 64 + kh * 32);                                                 \
        DOTF(C3, 64 + kh * 32 + 16);                                            \
        float a = (acc[0] + acc[1]) * (1.0f / 4096.0f);                         \
        if (kh == 0) a = fmaf(xj, CWX, a);                                      \
        s_part[kh][c] = a;                                                      \
        __syncthreads();  /* B: partials ready */                               \
        if (tid < H) {                                                          \
            const int h = tid;                                                  \
            const float gi = s_part[0][h]       + s_part[1][h]       + CBL.x;   \
            const float gf = s_part[0][H + h]   + s_part[1][H + h]   + CBL.y;   \
            const float go = s_part[0][2*H + h] + s_part[1][2*H + h] + CBL.z;   \
            const float gc = s_part[0][3*H + h] + s_part[1][3*H + h] + CBL.w;   \
            const float c_cand = sigmoidf_(gf) * c_t + sigmoidf_(gi) * tanhf_(gc); \
            const float h_row  = sigmoidf_(go) * tanhf_(c_cand);                \
            s_ht[mj * H + h] = h_row;                                           \
            accs += c_cand;                                                     \
            cnts += 1.0f;                                                       \
            const float tj = s_X[j];                                            \
            const float tn = (j < T - 1) ? s_X[j + 1] : (tj + 1.0f);            \
            const bool boundary = (j == len - 1) || (tn != tj);                 \
            if (boundary) { c_t = accs / fmaxf(cnts, 1.0f); accs = 0.0f; cnts = 0.0f; } \
            /* produce next step's decayed input (f32) */                       \
            const float dn  = s_X[3 * T + jn];                                  \
            const float dmn = fmaf(s_wdec[mjn], dn, s_bdec[mjn]);               \
            const float den = __expf(-fmaxf(0.0f, dmn));                        \
            const float hv  = (mjn == mj) ? h_row : s_ht[mjn * H + h];          \
            s_inp[h] = den * hv;                                                \
        }                                                                       \
        __syncthreads();  /* A: s_inp + h_t ready */                            \
    }

    int j = 0;
    while (j < len) {
        STEP(A0, A1, A2, A3, B0, B1, B2, B3, blA, blB, wxA, wxB); ++j;
        if (j >= len) break;
        STEP(B0, B1, B2, B3, A0, A1, A2, A3, blB, blA, wxB, wxA); ++j;
    }
    #undef STEP
    #undef DOTF

    // ---- epilogue ----
    if (tid < H) s_ct[tid] = c_t;
    __syncthreads();

    float z0 = 0.0f, z1 = 0.0f;
    for (int i = tid; i < FEATS; i += NTH) {
        const float f = s_feats[i];
        const float2 w = *(const float2*)(W_out + 2 * i);
        z0 = fmaf(f, w.x, z0);
        z1 = fmaf(f, w.y, z1);
    }
    #pragma unroll
    for (int off = 32; off > 0; off >>= 1) {
        z0 += __shfl_down(z0, off, 64);
        z1 += __shfl_down(z1, off, 64);
    }
    const int wave = tid >> 6, lane = tid & 63;
    if (lane == 0) { s_red[2 * wave] = z0; s_red[2 * wave + 1] = z1; }
    __syncthreads();
    if (tid == 0) {
        float a0 = b_out[0], a1 = b_out[1];
        #pragma unroll
        for (int w = 0; w < 16; ++w) { a0 += s_red[2 * w]; a1 += s_red[2 * w + 1]; }
        const float mx = fmaxf(a0, a1);
        const float e0 = __expf(a0 - mx), e1 = __expf(a1 - mx);
        const float inv = 1.0f / (e0 + e1);
        out[2 * b]     = e0 * inv;
        out[2 * b + 1] = e1 * inv;
    }
}

// ---------------- fp32 fallback (no-workspace path) ----------------
#define NTHREADS 512
__global__ __launch_bounds__(NTHREADS)
void lstm_scan_kernel(const float* __restrict__ X,
                      const int* __restrict__ lengths,
                      const float* __restrict__ W_lin,
                      const float* __restrict__ b_lin,
                      const float* __restrict__ W_dec,
                      const float* __restrict__ b_dec,
                      const float* __restrict__ W_out,
                      const float* __restrict__ b_out,
                      float* __restrict__ out)
{
    __shared__ float s_feats[FEATS];
    __shared__ float s_inp[H];
    __shared__ float s_part[4][H4];
    __shared__ float s_X[4 * T];
    __shared__ float s_wdec[NF];
    __shared__ float s_bdec[NF];
    __shared__ float s_red[16];

    float* s_ct = s_feats;
    float* s_ht = s_feats + H;

    const int tid = threadIdx.x;
    const int b   = blockIdx.x;
    const int g4  = tid & 127;
    const int kq  = tid >> 7;

    const float* Xb = X + b * 4 * T;
    const int len = lengths[b];

    for (int i = tid; i < NF * H; i += NTHREADS) s_ht[i] = 0.0f;
    for (int i = tid; i < 4 * T; i += NTHREADS) s_X[i] = Xb[i];
    if (tid < NF) { s_wdec[tid] = W_dec[tid]; s_bdec[tid] = b_dec[tid]; }
    __syncthreads();

    float c_t = 0.0f, acc = 0.0f, cnt = 0.0f;

    for (int j = 0; j < len; ++j) {
        const int   mj = (int)s_X[T + j];
        const float xj = s_X[2 * T + j];
        const float* Wf = W_lin + mj * WF_STRIDE;

        float bl0, bl1, bl2, bl3;
        if (tid < H) {
            const float dj    = s_X[3 * T + j];
            const float dm    = fmaf(s_wdec[mj], dj, s_bdec[mj]);
            const float decay = __expf(-fmaxf(0.0f, dm));
            s_inp[tid] = decay * s_ht[mj * H + tid];
            const int m4 = mj * H4;
            bl0 = b_lin[m4 + tid];
            bl1 = b_lin[m4 + H + tid];
            bl2 = b_lin[m4 + 2 * H + tid];
            bl3 = b_lin[m4 + 3 * H + tid];
        }
        __syncthreads();

        float4 a4 = make_float4(0.0f, 0.0f, 0.0f, 0.0f);
        {
            const float*  wr  = Wf + (1 + kq * 32) * H4 + 4 * g4;
            const float4* ivp = (const float4*)(s_inp + kq * 32);
            #pragma unroll
            for (int cc = 0; cc < 8; ++cc) {
                const float4 v = ivp[cc];
                const float* wrc = wr + (4 * cc) * H4;
                const float4 w0 = *(const float4*)(wrc);
                const float4 w1 = *(const float4*)(wrc + H4);
                const float4 w2 = *(const float4*)(wrc + 2 * H4);
                const float4 w3 = *(const float4*)(wrc + 3 * H4);
                a4.x = fmaf(v.x, w0.x, a4.x); a4.y = fmaf(v.x, w0.y, a4.y);
                a4.z = fmaf(v.x, w0.z, a4.z); a4.w = fmaf(v.x, w0.w, a4.w);
                a4.x = fmaf(v.y, w1.x, a4.x); a4.y = fmaf(v.y, w1.y, a4.y);
                a4.z = fmaf(v.y, w1.z, a4.z); a4.w = fmaf(v.y, w1.w, a4.w);
                a4.x = fmaf(v.z, w2.x, a4.x); a4.y = fmaf(v.z, w2.y, a4.y);
                a4.z = fmaf(v.z, w2.z, a4.z); a4.w = fmaf(v.z, w2.w, a4.w);
                a4.x = fmaf(v.w, w3.x, a4.x); a4.y = fmaf(v.w, w3.y, a4.y);
                a4.z = fmaf(v.w, w3.z, a4.z); a4.w = fmaf(v.w, w3.w, a4.w);
            }
        }
        if (kq == 0) {
            const float4 wv = *(const float4*)(Wf + 4 * g4);
            a4.x = fmaf(xj, wv.x, a4.x); a4.y = fmaf(xj, wv.y, a4.y);
            a4.z = fmaf(xj, wv.z, a4.z); a4.w = fmaf(xj, wv.w, a4.w);
        }
        *(float4*)(&s_part[kq][4 * g4]) = a4;
        __syncthreads();

        if (tid < H) {
            const int h = tid;
            const float gi = s_part[0][h]         + s_part[1][h]         + s_part[2][h]         + s_part[3][h]         + bl0;
            const float gf = s_part[0][H + h]     + s_part[1][H + h]     + s_part[2][H + h]     + s_part[3][H + h]     + bl1;
            const float go = s_part[0][2*H + h]   + s_part[1][2*H + h]   + s_part[2][2*H + h]   + s_part[3][2*H + h]   + bl2;
            const float gc = s_part[0][3*H + h]   + s_part[1][3*H + h]   + s_part[2][3*H + h]   + s_part[3][3*H + h]   + bl3;

            const float c_cand = sigmoidf_(gf) * c_t + sigmoidf_(gi) * tanhf_(gc);
            const float h_row  = sigmoidf_(go) * tanhf_(c_cand);
            s_ht[mj * H + h] = h_row;
            acc += c_cand;
            cnt += 1.0f;

            const float tj = s_X[j];
            const float tn = (j < T - 1) ? s_X[j + 1] : (tj + 1.0f);
            const bool boundary = (j == len - 1) || (tn != tj);
            if (boundary) { c_t = acc / fmaxf(cnt, 1.0f); acc = 0.0f; cnt = 0.0f; }
        }
        __syncthreads();
    }

    if (tid < H) s_ct[tid] = c_t;
    __syncthreads();

    float z0 = 0.0f, z1 = 0.0f;
    for (int i = tid; i < FEATS; i += NTHREADS) {
        const float f = s_feats[i];
        const float2 wv = *(const float2*)(W_out + 2 * i);
        z0 = fmaf(f, wv.x, z0);
        z1 = fmaf(f, wv.y, z1);
    }
    #pragma unroll
    for (int off = 32; off > 0; off >>= 1) {
        z0 += __shfl_down(z0, off, 64);
        z1 += __shfl_down(z1, off, 64);
    }
    const int wave = tid >> 6, lane = tid & 63;
    if (lane == 0) { s_red[2 * wave] = z0; s_red[2 * wave + 1] = z1; }
    __syncthreads();
    if (tid == 0) {
        float a0 = b_out[0], a1 = b_out[1];
        #pragma unroll
        for (int q = 0; q < 8; ++q) { a0 += s_red[2 * q]; a1 += s_red[2 * q + 1]; }
        const float mx = fmaxf(a0, a1);
        const float e0 = __expf(a0 - mx), e1 = __expf(a1 - mx);
        const float inv = 1.0f / (e0 + e1);
        out[2 * b]     = e0 * inv;
        out[2 * b + 1] = e1 * inv;
    }
}

extern "C" void kernel_launch(void* const* d_in, const int* in_sizes, int n_in,
                              void* d_out, int out_size, void* d_ws, size_t ws_size,
                              hipStream_t stream) {
    const float* X      = (const float*)d_in[0];
    const int*   lens   = (const int*)d_in[1];
    const float* W_lin  = (const float*)d_in[2];
    const float* b_lin  = (const float*)d_in[3];
    const float* W_dec  = (const float*)d_in[4];
    const float* b_dec  = (const float*)d_in[5];
    const float* W_out  = (const float*)d_in[6];
    const float* b_out  = (const float*)d_in[7];
    float* out = (float*)d_out;

    if (ws_size >= PACK8_BYTES) {
        uint4* pack = (uint4*)d_ws;
        hipLaunchKernelGGL(repack8_kernel, dim3(PACK8_U4 / 256), dim3(256), 0, stream,
                           W_lin, pack);
        hipLaunchKernelGGL(lstm_scan_fp8_v2, dim3(BATCH), dim3(NTH), 0, stream,
                           X, lens, W_lin, b_lin, W_dec, b_dec, W_out, b_out, pack, out);
    } else {
        hipLaunchKernelGGL(lstm_scan_kernel, dim3(BATCH), dim3(NTHREADS), 0, stream,
                           X, lens, W_lin, b_lin, W_dec, b_dec, W_out, b_out, out);
    }
}